// Round 6
// baseline (143.851 us; speedup 1.0000x reference)
//
#include <hip/hip_runtime.h>

#define DIM   64
#define KCB   1024
#define NROW  32768

typedef float floatx4 __attribute__((ext_vector_type(4)));
typedef __bf16 bf16x8 __attribute__((ext_vector_type(8)));
typedef unsigned int uint;

union ABu { bf16x8 v; __bf16 h[8]; uint4 u4; };

// ---------------------------------------------------------------------------
// Single fused kernel, codebook-in-registers structure.
// WHY (R5 counters): tile+barrier design was latency-bound (all pipes <22%,
// occupancy 19%) -- every __syncthreads drains vmcnt(0) for the next tile's
// DMA, and the occupancy identity rows/wave * waves/CU = 512 caps resident
// waves. Here B never touches LDS: each of 4 waves holds 256 codewords
// (its column quarter) in 128 VGPRs + 16 iv regs, loaded ONCE from fp32 cbg
// (L2-shared across blocks). Rows stream through registers with a one-deep
// fp32 prefetch; per 16-row tile: 32 MFMA + key-pack + 4-level shfl partial
// argmin -> LDS slot (no sync). ONE __syncthreads, then emit: 4-way min
// combine, codeword gather (cbg L2-hot), dense 1KB/wave out writes, loss.
// Grid 512 = chunk(7b, 256 rows) | g(2b) -> exactly 2 blocks/CU, one cohort.
// Per-CU budgets: MFMA 19.9K cyc (critical), key-VALU ~8K/SIMD, LDS trivial,
// HBM 69MB streamed continuously (no burst phases).
// ---------------------------------------------------------------------------
extern "C" __global__ void __launch_bounds__(256, 2)
vq_fused(const float* __restrict__ latents, const float* __restrict__ cbg,
         float* __restrict__ out, float* __restrict__ loss)
{
    __shared__ uint  part_km[4][256];     // per-wave partial argmin keys, 4 KB
    __shared__ float xsq_lds[256];        // row norms, 1 KB
    __shared__ float lsum_part[4];

    const int tid  = threadIdx.x;
    const int wave = tid >> 6;
    const int lane = tid & 63;
    const int l15  = lane & 15;
    const int quad = lane >> 4;

    const int bid   = blockIdx.x;
    const int chunk = bid & 127;          // bid%8 round-robins XCDs
    const int g     = bid >> 7;
    const int row0  = chunk * 256;        // block owns 256 latent rows

    const float4* __restrict__ lsrc = (const float4*)latents;
    const float4* __restrict__ cb4  = (const float4*)cbg + (size_t)g * (KCB * 16);

    // ---- issue first A prefetch before the B prologue (independent) ----
    float4 nf0, nf1, nf2, nf3;
    {
        const size_t rb = (size_t)(row0 + l15) * 64 + g * 16 + (size_t)quad * 2;
        nf0 = lsrc[rb];     nf1 = lsrc[rb + 1];
        nf2 = lsrc[rb + 8]; nf3 = lsrc[rb + 9];
    }

    // ---- B prologue: wave's 256 codewords -> 128 VGPRs + iv[16] ----
    // lane(l15,quad) holds col=wave*256+ct*16+l15, dims [quad*8+ks*32,+8)
    bf16x8 bfrag[16][2];
    float  iv[16];
    #pragma unroll
    for (int ct = 0; ct < 16; ++ct) {
        const size_t cbase = (size_t)(wave * 256 + ct * 16 + l15) * 16
                           + (size_t)quad * 2;
        float cs = 0.f;
        #pragma unroll
        for (int ks = 0; ks < 2; ++ks) {
            const float4 f0 = cb4[cbase + ks * 8];
            const float4 f1 = cb4[cbase + ks * 8 + 1];
            cs += f0.x*f0.x + f0.y*f0.y + f0.z*f0.z + f0.w*f0.w
                + f1.x*f1.x + f1.y*f1.y + f1.z*f1.z + f1.w*f1.w;
            ABu t;
            t.h[0]=(__bf16)f0.x; t.h[1]=(__bf16)f0.y; t.h[2]=(__bf16)f0.z; t.h[3]=(__bf16)f0.w;
            t.h[4]=(__bf16)f1.x; t.h[5]=(__bf16)f1.y; t.h[6]=(__bf16)f1.z; t.h[7]=(__bf16)f1.w;
            bfrag[ct][ks] = t.v;
        }
        cs += __shfl_xor(cs, 16);
        cs += __shfl_xor(cs, 32);         // full 64-dim csq
        iv[ct] = -0.5f * cs - 0.5f;       // scores < 0 (data margin ~10x)
    }

    const uint kc0 = (uint)(wave * 256 + l15);

    // ---- row loop: 16 tiles x 16 rows, reg-prefetched, barrier-free ----
    #pragma unroll 2
    for (int rtile = 0; rtile < 16; ++rtile) {
        const float4 cf0 = nf0, cf1 = nf1, cf2 = nf2, cf3 = nf3;
        if (rtile < 15) {                 // prefetch next tile's fp32 A
            const size_t rb = (size_t)(row0 + (rtile + 1) * 16 + l15) * 64
                            + g * 16 + (size_t)quad * 2;
            nf0 = lsrc[rb];     nf1 = lsrc[rb + 1];
            nf2 = lsrc[rb + 8]; nf3 = lsrc[rb + 9];
        }
        // cvt + row norm (all 4 waves load identical A; redundant but cheap)
        float s = cf0.x*cf0.x + cf0.y*cf0.y + cf0.z*cf0.z + cf0.w*cf0.w
                + cf1.x*cf1.x + cf1.y*cf1.y + cf1.z*cf1.z + cf1.w*cf1.w
                + cf2.x*cf2.x + cf2.y*cf2.y + cf2.z*cf2.z + cf2.w*cf2.w
                + cf3.x*cf3.x + cf3.y*cf3.y + cf3.z*cf3.z + cf3.w*cf3.w;
        s += __shfl_xor(s, 16);
        s += __shfl_xor(s, 32);
        if (wave == 0 && quad == 0) xsq_lds[rtile * 16 + l15] = s;

        ABu a0, a1;
        a0.h[0]=(__bf16)cf0.x; a0.h[1]=(__bf16)cf0.y; a0.h[2]=(__bf16)cf0.z; a0.h[3]=(__bf16)cf0.w;
        a0.h[4]=(__bf16)cf1.x; a0.h[5]=(__bf16)cf1.y; a0.h[6]=(__bf16)cf1.z; a0.h[7]=(__bf16)cf1.w;
        a1.h[0]=(__bf16)cf2.x; a1.h[1]=(__bf16)cf2.y; a1.h[2]=(__bf16)cf2.z; a1.h[3]=(__bf16)cf2.w;
        a1.h[4]=(__bf16)cf3.x; a1.h[5]=(__bf16)cf3.y; a1.h[6]=(__bf16)cf3.z; a1.h[7]=(__bf16)cf3.w;

        uint b0 = 0xFFFFFFFFu, b1 = 0xFFFFFFFFu, b2 = 0xFFFFFFFFu, b3 = 0xFFFFFFFFu;
        #pragma unroll
        for (int ct = 0; ct < 16; ++ct) {
            const float v = iv[ct];
            const floatx4 accb = { v, v, v, v };
            floatx4 acc = __builtin_amdgcn_mfma_f32_16x16x32_bf16(a0.v, bfrag[ct][0], accb, 0, 0, 0);
            acc = __builtin_amdgcn_mfma_f32_16x16x32_bf16(a1.v, bfrag[ct][1], acc, 0, 0, 0);
            const uint kcol = kc0 + (uint)(ct * 16);
            // (bits & mask) | kcol -> v_and_or_b32; min_u32 on negative floats
            uint k;
            k = (__float_as_uint(acc[0]) & 0xFFFFFC00u) | kcol; b0 = b0 < k ? b0 : k;
            k = (__float_as_uint(acc[1]) & 0xFFFFFC00u) | kcol; b1 = b1 < k ? b1 : k;
            k = (__float_as_uint(acc[2]) & 0xFFFFFC00u) | kcol; b2 = b2 < k ? b2 : k;
            k = (__float_as_uint(acc[3]) & 0xFFFFFC00u) | kcol; b3 = b3 < k ? b3 : k;
        }
        // 16-lane column min (wave's 256-cw partial argmin per row)
        #pragma unroll
        for (int m = 1; m <= 8; m <<= 1) {
            uint o;
            o = (uint)__shfl_xor((int)b0, m); b0 = o < b0 ? o : b0;
            o = (uint)__shfl_xor((int)b1, m); b1 = o < b1 ? o : b1;
            o = (uint)__shfl_xor((int)b2, m); b2 = o < b2 ? o : b2;
            o = (uint)__shfl_xor((int)b3, m); b3 = o < b3 ? o : b3;
        }
        if (l15 == 0) {                   // rows quad*4+0..3 of this tile
            part_km[wave][rtile * 16 + quad * 4 + 0] = b0;
            part_km[wave][rtile * 16 + quad * 4 + 1] = b1;
            part_km[wave][rtile * 16 + quad * 4 + 2] = b2;
            part_km[wave][rtile * 16 + quad * 4 + 3] = b3;
        }
    }
    __syncthreads();                      // the ONLY barrier

    // ---- emit: combine 4 wave-partials, gather codeword, write out+loss ----
    float lsum = 0.f;
    float4* __restrict__ out4 = (float4*)out;
    #pragma unroll 4
    for (int jj = 0; jj < 16; ++jj) {
        const int row = wave * 64 + jj * 4 + quad;      // block-local row
        const uint k0 = part_km[0][row], k1 = part_km[1][row];
        const uint k2 = part_km[2][row], k3 = part_km[3][row];
        uint kmin = k0 < k1 ? k0 : k1;
        const uint km2 = k2 < k3 ? k2 : k3;
        kmin = kmin < km2 ? kmin : km2;
        const int kidx = (int)(kmin & 1023u);
        // 16 lanes x float4 = 256B/row; 4 rows/instr = dense 1KB wave writes
        out4[(size_t)(row0 + row) * 64 + g * 16 + l15] = cb4[(size_t)kidx * 16 + l15];
        const float sc = __uint_as_float(kmin & 0xFFFFFC00u);
        const float term = xsq_lds[row] - 2.f * sc - 1.f;   // exact sq dist
        lsum += (l15 == 0) ? term : 0.f;
    }
    lsum += __shfl_xor(lsum, 16);
    lsum += __shfl_xor(lsum, 32);         // sum the 4 quad partials
    if (lane == 0) lsum_part[wave] = lsum;
    __syncthreads();
    if (tid == 0)
        atomicAdd(loss, (lsum_part[0] + lsum_part[1] + lsum_part[2] + lsum_part[3])
                        * (1.25f / 8388608.0f));
}

extern "C" void kernel_launch(void* const* d_in, const int* in_sizes, int n_in,
                              void* d_out, int out_size, void* d_ws, size_t ws_size,
                              hipStream_t stream)
{
    const float* latents = (const float*)d_in[0];
    const float* cbg     = (const float*)d_in[1];
    float* out   = (float*)d_out;
    float* lossp = out + 8388608;

    hipMemsetAsync(lossp, 0, sizeof(float), stream);   // zero loss (4 B)
    vq_fused<<<dim3(512), dim3(256), 0, stream>>>(latents, cbg, out, lossp);
}

// Round 7
// 111.878 us; speedup vs baseline: 1.2858x; 1.2858x over previous
//
#include <hip/hip_runtime.h>

#define DIM   64
#define KCB   1024
#define KT2   128    // codewords per LDS tile
#define NROW  32768

typedef float floatx4 __attribute__((ext_vector_type(4)));
typedef __bf16 bf16x8 __attribute__((ext_vector_type(8)));
typedef unsigned int uint;

union ABu { bf16x8 v; __bf16 h[8]; uint4 u4; };

// ---------------------------------------------------------------------------
// Prep (codebook only): fp32 codebook -> bf16 rows with 16B-chunk XOR swizzle
// (LDS image) + initv = -0.5*csq - 0.5 (makes every score < 0) + loss = 0.
// 64 blocks, thread = QUARTER codeword (16 elems), csq via 4-lane shfl.
// ---------------------------------------------------------------------------
extern "C" __global__ void __launch_bounds__(256)
vq_prep_cb(const float* __restrict__ cbg, uint* __restrict__ cb_bf,
           float* __restrict__ initv, float* __restrict__ loss)
{
    const int q = blockIdx.x * 256 + threadIdx.x;   // 0..16383 quarter-rows
    const int k = q >> 2;                            // codeword row 0..4095
    const int p = q & 3;                             // quarter within row
    const float4* __restrict__ src = (const float4*)cbg + (size_t)k * 16 + p * 4;
    uint* __restrict__ drow = cb_bf + (size_t)k * 32;
    float csq = 0.f;
    #pragma unroll
    for (int h = 0; h < 2; ++h) {                    // 2 chunks of 8 floats
        const float4 f0 = src[h * 2];
        const float4 f1 = src[h * 2 + 1];
        csq += f0.x*f0.x + f0.y*f0.y + f0.z*f0.z + f0.w*f0.w
             + f1.x*f1.x + f1.y*f1.y + f1.z*f1.z + f1.w*f1.w;
        ABu t;
        t.h[0]=(__bf16)f0.x; t.h[1]=(__bf16)f0.y; t.h[2]=(__bf16)f0.z; t.h[3]=(__bf16)f0.w;
        t.h[4]=(__bf16)f1.x; t.h[5]=(__bf16)f1.y; t.h[6]=(__bf16)f1.z; t.h[7]=(__bf16)f1.w;
        const int c  = p * 2 + h;
        const int dc = c ^ (k & 7);                  // LDS-bank XOR swizzle
        *(uint4*)&drow[dc * 4] = t.u4;
    }
    csq += __shfl_xor(csq, 1);
    csq += __shfl_xor(csq, 2);                       // sum over the 4 quarters
    if (p == 0) initv[k] = -0.5f * csq - 0.5f;
    if (q == 0) *loss = 0.f;
}

// ---------------------------------------------------------------------------
// Fused score+emit, K-SPLIT waves. Grid 512 = chunk(7b, 256 rows) | g(2b);
// 512 thr = 8 waves = 4 row-slices (rw, 64 rows each, rt=4) x 2 K-halves
// (kh, 512 cw each). WHY: waves/CU = 32/rt when K is unsplit -- rt=2 was
// LDS-read-bound (R3, ~13us/CU LDS pipe), rt=4 halved occupancy and went
// latency-bound (R5, 58.5us). Splitting K gives rt=4's LDS economy (2x
// ds_read_b128 feeds 8 MFMAs) AT 16 waves/CU. Per-CU: LDS 6.4us, MFMA
// 8.3us, keypack-VALU 4.3us, HBM 67MB=10.7us (ceiling). Each K-half has its
// own double-buffered 2x16KB LDS stream (4 barriers/block vs R3's 8); the
// two halves' partial argmins combine via one LDS round + barrier. VGPR ~90
// pinned by launch_bounds(512,4) -> no spill (R6's failure). LDS 71KB ->
// 2 blocks/CU. Epilogue: gather winning fp32 codeword (L2-hot) -> out+loss.
// ---------------------------------------------------------------------------
extern "C" __global__ void __launch_bounds__(512, 4)
vq_score(const float* __restrict__ latents, const uint* __restrict__ cb_bf,
         const float* __restrict__ initv, const float* __restrict__ cbg,
         float* __restrict__ out, float* __restrict__ loss)
{
    __shared__ __attribute__((aligned(16))) uint  cb_lds[2][2][KT2 * 32]; // 64KB
    __shared__ __attribute__((aligned(16))) float iv_lds[KCB];            // 4KB
    __shared__ uint  part_km[2][256];                                     // 2KB
    __shared__ float xsq_lds[256];                                        // 1KB
    __shared__ float lsum_part[8];

    const int tid  = threadIdx.x;
    const int w    = tid >> 6;            // 0..7
    const int lane = tid & 63;
    const int l15  = lane & 15;
    const int quad = lane >> 4;
    const int kh   = w >> 2;              // K-half 0/1 (512 cw)
    const int rw   = w & 3;               // row-slice 0..3 (64 rows)

    const int bid   = blockIdx.x;
    const int chunk = bid & 127;          // bid%8 round-robins XCDs; the 4
    const int g     = bid >> 7;           // g-siblings share latent rows in L2
    const int row0  = chunk * 256;
    const int wRow0 = row0 + rw * 64;

    // wave's K-half codebook image base (bf16, pre-swizzled)
    const uint* gcb = cb_bf + (size_t)g * (KCB * 32) + (size_t)kh * (512 * 32);

    // ---- prologue: DMA tile0 of this wave's stream + iv (waves 0-3) ----
    {
        #pragma unroll
        for (int i = 0; i < 4; ++i) {
            const int off = rw * 1024 + i * 256;             // uint words
            __builtin_amdgcn_global_load_lds(
                (const __attribute__((address_space(1))) uint*)(gcb + off + lane * 4),
                (__attribute__((address_space(3))) uint*)&cb_lds[kh][0][off], 16, 0, 0);
        }
        if (kh == 0) {
            const uint* isrc = (const uint*)(initv + g * KCB) + rw * 256;
            __builtin_amdgcn_global_load_lds(
                (const __attribute__((address_space(1))) uint*)(isrc + lane * 4),
                (__attribute__((address_space(3))) uint*)&iv_lds[rw * 256], 16, 0, 0);
        }
    }

    // ---- A fragments from fp32 latents + xsq, in-register (loop-invariant).
    // kh=1 waves re-load the same rows as kh=0: L1-hot, cheaper than a sync.
    bf16x8 afrag[4][2];
    {
        const float4* __restrict__ lsrc = (const float4*)latents;
        #pragma unroll
        for (int rt = 0; rt < 4; ++rt) {
            const size_t rb = (size_t)(wRow0 + rt * 16 + l15) * 64 + g * 16
                            + (size_t)quad * 2;
            float s = 0.f;
            #pragma unroll
            for (int ks = 0; ks < 2; ++ks) {
                const float4 f0 = lsrc[rb + ks * 8];
                const float4 f1 = lsrc[rb + ks * 8 + 1];
                s += f0.x*f0.x + f0.y*f0.y + f0.z*f0.z + f0.w*f0.w
                   + f1.x*f1.x + f1.y*f1.y + f1.z*f1.z + f1.w*f1.w;
                ABu t;
                t.h[0]=(__bf16)f0.x; t.h[1]=(__bf16)f0.y; t.h[2]=(__bf16)f0.z; t.h[3]=(__bf16)f0.w;
                t.h[4]=(__bf16)f1.x; t.h[5]=(__bf16)f1.y; t.h[6]=(__bf16)f1.z; t.h[7]=(__bf16)f1.w;
                afrag[rt][ks] = t.v;
            }
            s += __shfl_xor(s, 16);
            s += __shfl_xor(s, 32);       // full 64-dim row sum
            if (kh == 0 && quad == 0) xsq_lds[rw * 64 + rt * 16 + l15] = s;
        }
    }
    __syncthreads();                      // tile0 (both streams) + iv + xsq

    uint best[4][4];
    #pragma unroll
    for (int rt = 0; rt < 4; ++rt)
        #pragma unroll
        for (int r = 0; r < 4; ++r) best[rt][r] = 0xFFFFFFFFu;

    const int o0  = l15 * 32;
    const int sw0 = (quad       ^ (l15 & 7)) << 2;
    const int sw1 = ((quad + 4) ^ (l15 & 7)) << 2;

    #pragma unroll
    for (int tile = 0; tile < 4; ++tile) {
        // issue next tile's DMA first: overlaps the 8 t-iters of MFMA below
        if (tile < 3) {
            const uint* gsrc = gcb + (tile + 1) * (KT2 * 32);
            #pragma unroll
            for (int i = 0; i < 4; ++i) {
                const int off = rw * 1024 + i * 256;
                __builtin_amdgcn_global_load_lds(
                    (const __attribute__((address_space(1))) uint*)(gsrc + off + lane * 4),
                    (__attribute__((address_space(3))) uint*)&cb_lds[kh][(tile + 1) & 1][off], 16, 0, 0);
            }
        }

        const uint*  bbase0 = &cb_lds[kh][tile & 1][o0 + sw0];
        const uint*  bbase1 = &cb_lds[kh][tile & 1][o0 + sw1];
        const float* ivb    = &iv_lds[kh * 512 + tile * KT2 + l15];
        const uint   kcol0  = (uint)(kh * 512 + tile * KT2 + l15);

        #pragma unroll 2
        for (int t = 0; t < 8; ++t) {
            const float v = ivb[t * 16];
            ABu b0, b1;
            b0.u4 = *(const uint4*)(bbase0 + t * 512);
            b1.u4 = *(const uint4*)(bbase1 + t * 512);
            const uint kcol = kcol0 + t * 16;
            const floatx4 accb = { v, v, v, v };   // shared C operand (D != C)
            #pragma unroll
            for (int rt = 0; rt < 4; ++rt) {
                floatx4 acc = __builtin_amdgcn_mfma_f32_16x16x32_bf16(afrag[rt][0], b0.v, accb, 0, 0, 0);
                acc = __builtin_amdgcn_mfma_f32_16x16x32_bf16(afrag[rt][1], b1.v, acc, 0, 0, 0);
                // score < 0 -> fp32 bits monotone decreasing; pack idx, min_u32
                #pragma unroll
                for (int r = 0; r < 4; ++r) {
                    const uint key = (__float_as_uint(acc[r]) & 0xFFFFFC00u) | kcol;
                    best[rt][r] = best[rt][r] < key ? best[rt][r] : key;
                }
            }
        }
        if (tile < 3) __syncthreads();    // drains next-tile DMA + frees buf
    }

    // ---- per-wave 16-lane column reduce -> K-half partial keys ----
    #pragma unroll
    for (int rt = 0; rt < 4; ++rt)
        #pragma unroll
        for (int r = 0; r < 4; ++r) {
            uint kmin = best[rt][r];
            #pragma unroll
            for (int m = 1; m <= 8; m <<= 1) {
                const uint o = (uint)__shfl_xor((int)kmin, m);
                kmin = o < kmin ? o : kmin;
            }
            if (l15 == 0)
                part_km[kh][rw * 64 + rt * 16 + quad * 4 + r] = kmin;
        }
    __syncthreads();

    // ---- emit: combine K-halves, gather fp32 codeword, write out + loss ----
    float lsum = 0.f;
    const float4* __restrict__ cb4 = (const float4*)cbg + (size_t)g * (KCB * 16);
    float4* __restrict__ out4 = (float4*)out;
    #pragma unroll
    for (int jj = 0; jj < 8; ++jj) {
        const int row = w * 32 + jj * 4 + quad;             // block-local row
        const uint k0 = part_km[0][row];
        const uint k1 = part_km[1][row];
        const uint kmin = k0 < k1 ? k0 : k1;
        const int  kidx = (int)(kmin & 1023u);
        // 16 lanes x float4 = 256B/row; 4 rows/instr = dense 1KB wave writes
        out4[(size_t)(row0 + row) * 64 + g * 16 + l15] = cb4[(size_t)kidx * 16 + l15];
        if (l15 == 0) {
            const float sc = __uint_as_float(kmin & 0xFFFFFC00u);
            lsum += xsq_lds[row] - 2.f * sc - 1.f;          // exact sq dist
        }
    }
    lsum += __shfl_xor(lsum, 16);
    lsum += __shfl_xor(lsum, 32);         // sum the 4 quad partials
    if (lane == 0) lsum_part[w] = lsum;
    __syncthreads();
    if (tid == 0) {
        float t = 0.f;
        #pragma unroll
        for (int i = 0; i < 8; ++i) t += lsum_part[i];
        atomicAdd(loss, t * (1.25f / 8388608.0f));
    }
}

extern "C" void kernel_launch(void* const* d_in, const int* in_sizes, int n_in,
                              void* d_out, int out_size, void* d_ws, size_t ws_size,
                              hipStream_t stream)
{
    const float* latents = (const float*)d_in[0];
    const float* cbg     = (const float*)d_in[1];
    float* out   = (float*)d_out;
    float* lossp = out + 8388608;

    uint*  cb_bf = (uint*)d_ws;                          // 512 KB
    float* initv = (float*)((uint*)d_ws + 4096 * 32);    // 16 KB

    vq_prep_cb<<<dim3(64),  dim3(256), 0, stream>>>(cbg, cb_bf, initv, lossp);
    vq_score  <<<dim3(512), dim3(512), 0, stream>>>(latents, cb_bf, initv,
                                                    cbg, out, lossp);
}